// Round 6
// baseline (125.265 us; speedup 1.0000x reference)
//
#include <hip/hip_runtime.h>

#define GQ    8192           // bs(32) * Gn(256)
#define BLKG  8              // groups per block (8 waves, 512 threads)
#define NBLK  (GQ / BLKG)    // 1024 blocks
#define MROW  132            // LDS row stride in floats (128 + 4: bank spread)
#define STG   (64 * MROW)    // staging floats per pass (64 channels)
#define SIMW  72             // per-wave sim scratch floats
#define SQRT5 2.23606797749978969f   // sqrt(1/T): folded so sim = dot/T

// DPP add helpers (VALU pipe, no LDS): quad_perm 0xB1 = xor1, 0x4E = xor2,
// row_shr/bcast chain for full wave sum (total lands in lane 63).
template<int CTRL>
__device__ __forceinline__ float dpp_add(float v) {
    int t = __builtin_amdgcn_update_dpp(0, __float_as_int(v), CTRL, 0xF, 0xF, true);
    return v + __int_as_float(t);
}
__device__ __forceinline__ float wave_sum64(float v) {
    v = dpp_add<0x111>(v);   // row_shr:1
    v = dpp_add<0x112>(v);   // row_shr:2
    v = dpp_add<0x114>(v);   // row_shr:4
    v = dpp_add<0x118>(v);   // row_shr:8
    v = dpp_add<0x142>(v);   // row_bcast:15
    v = dpp_add<0x143>(v);   // row_bcast:31 -> lane 63 = wave total
    return v;
}

// Block = 8 waves = 8 consecutive groups (same batch b).
// TWO-PASS staging (32KB halves), LDS ~36KB -> 4 blocks/CU = 32 waves/CU.
// PIPELINED: pass-B global loads issue right after the pass-A barrier so their
// HBM latency hides under consume-A (ds_read + bucket switch).
// Gram rows reduce-scattered over 64 lanes (xor32/16/8 shfl + xor4 shfl +
// xor2/xor1 DPP); s88 via DPP wave sum. LSE lane-parallel (lane r = row r).
__global__ __launch_bounds__(64 * BLKG, 8) void group_loss_kernel(
    const int*   __restrict__ labs,   // [G*16]
    const float* __restrict__ feats,  // [32,128,256,16]
    const int*   __restrict__ idxs,   // [G*16]
    const float* __restrict__ ctx,    // [128]
    float2*      __restrict__ ws)     // [G] {gl*gv, gv}
{
    __shared__ float SH[STG + BLKG * SIMW];     // 36096 B -> 4 blocks/CU

    const int l  = threadIdx.x & 63;
    const int w  = threadIdx.x >> 6;            // wave id = local group id
    const int g0 = blockIdx.x * BLKG;
    const int g  = g0 + w;
    const int b  = g0 >> 8;                     // 8 | 256 -> same b for block
    const int gn0 = g0 & 255;
    float* SIM = SH + STG + w * SIMW;

    const float* base = feats + (long)b * 524288 + (long)gn0 * 16;
    const int lo = l & 31;
    const int ch = w * 8 + (l >> 5);            // this thread's even channel base

    // ---- label/index loads (issue early) -----------------------------------
    int myidx = -1, mylab = -2;
    if (l < 16) { myidx = idxs[g * 16 + l]; mylab = labs[g * 16 + l]; }
    const float cx0 = ctx[l], cx1 = ctx[l + 64];

    // ---- stage pass A (channels 0..63): 4 bursts per thread ----------------
    float4 st[4];
    #pragma unroll
    for (int k = 0; k < 4; ++k)
        st[k] = *(const float4*)(base + (long)(ch + 2 * k) * 4096 + lo * 4);

    // ---- ballots while stage-A loads are in flight -------------------------
    unsigned long long mm = ~0ull;
    #pragma unroll
    for (int bit = 0; bit < 6; ++bit) {
        const unsigned long long bb = __ballot((myidx >> bit) & 1);
        mm &= ((myidx >> bit) & 1) ? bb : ~bb;
    }
    const bool dup = (mm & ((1ull << l) - 1) & 0xFFFFull) != 0ull;
    const int u = __popcll(__ballot((l < 16) && !dup));

    const bool valid = l < u;
    const int bid = valid ? (mylab + 1) : 255;  // bucket 0 = bg(-1), 1..8 = fg

    int cnt9[9];
    #pragma unroll
    for (int r = 0; r < 9; ++r) cnt9[r] = __popcll(__ballot(bid == r));
    const bool has_bg = cnt9[0] > 0;
    int fg_count = 0, pm = 0;
    #pragma unroll
    for (int r = 1; r < 9; ++r)
        if (cnt9[r] > 0) { ++fg_count; pm |= 1 << r; }

    // ---- write pass A to LDS ------------------------------------------------
    #pragma unroll
    for (int k = 0; k < 4; ++k)
        *(float4*)(SH + (ch + 2 * k) * MROW + lo * 4) = st[k];
    __syncthreads();

    // ---- ISSUE pass-B loads NOW (hide HBM latency under consume A) ---------
    #pragma unroll
    for (int k = 0; k < 4; ++k)
        st[k] = *(const float4*)(base + (long)(64 + ch + 2 * k) * 4096 + lo * 4);
    __builtin_amdgcn_sched_barrier(0);          // pin load issue before consume

    float m0[9] = {0,0,0,0,0,0,0,0,0};
    float m1[9] = {0,0,0,0,0,0,0,0,0};

    // ---- consume pass A: lane l = channel l, chunked switch ----------------
    {
        const float* R = SH + l * MROW + w * 16;
        #pragma unroll
        for (int q = 0; q < 4; ++q) {
            const float4 x = *(const float4*)(R + 4 * q);
            #pragma unroll
            for (int e = 0; e < 4; ++e) {
                const int s = 4 * q + e;
                if (s < u) {                                      // uniform
                    const int bs = __builtin_amdgcn_readlane(bid, s);
                    const float v = (e == 0) ? x.x : (e == 1) ? x.y
                                  : (e == 2) ? x.z : x.w;
                    switch (bs) {
                        case 0: m0[0] += v; break;  case 1: m0[1] += v; break;
                        case 2: m0[2] += v; break;  case 3: m0[3] += v; break;
                        case 4: m0[4] += v; break;  case 5: m0[5] += v; break;
                        case 6: m0[6] += v; break;  case 7: m0[7] += v; break;
                        case 8: m0[8] += v; break;
                    }
                }
            }
        }
    }
    __syncthreads();                             // A reads done; safe to restage

    // ---- write pass B (loads already near-complete) ------------------------
    #pragma unroll
    for (int k = 0; k < 4; ++k)
        *(float4*)(SH + (ch + 2 * k) * MROW + lo * 4) = st[k];
    __syncthreads();

    // ---- consume pass B: lane l = channel l+64 -----------------------------
    {
        const float* R = SH + l * MROW + w * 16;
        #pragma unroll
        for (int q = 0; q < 4; ++q) {
            const float4 x = *(const float4*)(R + 4 * q);
            #pragma unroll
            for (int e = 0; e < 4; ++e) {
                const int s = 4 * q + e;
                if (s < u) {
                    const int bs = __builtin_amdgcn_readlane(bid, s);
                    const float v = (e == 0) ? x.x : (e == 1) ? x.y
                                  : (e == 2) ? x.z : x.w;
                    switch (bs) {
                        case 0: m1[0] += v; break;  case 1: m1[1] += v; break;
                        case 2: m1[2] += v; break;  case 3: m1[3] += v; break;
                        case 4: m1[4] += v; break;  case 5: m1[5] += v; break;
                        case 6: m1[6] += v; break;  case 7: m1[7] += v; break;
                        case 8: m1[8] += v; break;
                    }
                }
            }
        }
    }

    // ---- means scaled by sqrt(5) (carries 1/T in pair products) ------------
    #pragma unroll
    for (int r = 0; r < 9; ++r) {
        const float sc = SQRT5 / (float)(cnt9[r] > 0 ? cnt9[r] : 1);
        m0[r] *= sc; m1[r] *= sc;
    }
    if (!has_bg) { m0[0] = cx0 * SQRT5; m1[0] = cx1 * SQRT5; }

    // ---- Gram rows 1..8 via reduce-scatter: lane group l>>3 owns slot ------
    #pragma unroll
    for (int r = 1; r <= 8; ++r) {
        float p[8];
        #pragma unroll
        for (int j = 0; j < 8; ++j)
            p[j] = m0[r] * m0[j] + m1[r] * m1[j];
        #pragma unroll
        for (int i = 0; i < 4; ++i) {            // d=32 scatter
            const float send = (l & 32) ? p[i] : p[i + 4];
            const float recv = __shfl_xor(send, 32);
            p[i] = ((l & 32) ? p[i + 4] : p[i]) + recv;
        }
        #pragma unroll
        for (int i = 0; i < 2; ++i) {            // d=16 scatter
            const float send = (l & 16) ? p[i] : p[i + 2];
            const float recv = __shfl_xor(send, 16);
            p[i] = ((l & 16) ? p[i + 2] : p[i]) + recv;
        }
        {                                        // d=8 scatter
            const float send = (l & 8) ? p[0] : p[1];
            const float recv = __shfl_xor(send, 8);
            p[0] = ((l & 8) ? p[1] : p[0]) + recv;
        }
        p[0] += __shfl_xor(p[0], 4);             // d=4 (ds_swizzle)
        p[0] = dpp_add<0x4E>(p[0]);              // d=2 (DPP quad_perm 2,3,0,1)
        p[0] = dpp_add<0xB1>(p[0]);              // d=1 (DPP quad_perm 1,0,3,2)
        if ((l & 7) == 0) SIM[(r - 1) * 8 + (l >> 3)] = p[0];
    }
    // sim[8][8]: DPP wave sum -> lane 63 -> uniform via readlane
    float s88 = wave_sum64(m0[8] * m0[8] + m1[8] * m1[8]);
    s88 = __int_as_float(__builtin_amdgcn_readlane(__float_as_int(s88), 63));

    // ---- lane-parallel masked LSE: lane r = row r (1..8) -------------------
    const int cm = pm | 1;                       // col 0 (bg/ctx) always valid
    const float NINF = __int_as_float(0xFF800000);
    float li = 0.0f;
    if (l >= 1 && l <= 8) {
        const float* Rw = SIM + (l - 1) * 8;
        const float4 ra = *(const float4*)(Rw);
        const float4 rb = *(const float4*)(Rw + 4);
        const float s8 = SIM[56 + l];            // junk for l==8 (in-range)
        float srow[9] = { ra.x, ra.y, ra.z, ra.w, rb.x, rb.y, rb.z, rb.w,
                          (l == 8) ? s88 : s8 };
        float vmax = NINF, diag = 0.0f, v[9];
        #pragma unroll
        for (int j = 0; j < 9; ++j) {
            v[j] = ((cm >> j) & 1) ? srow[j] : NINF;
            vmax = fmaxf(vmax, v[j]);
            if (j >= 1) diag = (l == j) ? srow[j] : diag;
        }
        float se = 0.0f;
        #pragma unroll
        for (int j = 0; j < 9; ++j) se += __expf(v[j] - vmax);  // exp(-inf)=0
        li = vmax + __logf(se) - diag;
        li = ((pm >> l) & 1) ? li : 0.0f;        // absent row contributes 0
    }

    // ---- sum li over lanes 1..8 -> lane 0; single float2 store -------------
    float ssum = li;
    ssum += __shfl_down(ssum, 8);
    ssum += __shfl_down(ssum, 4);
    ssum += __shfl_down(ssum, 2);
    ssum += __shfl_down(ssum, 1);
    if (l == 0) {
        float2 r;
        r.x = ssum / (float)(fg_count > 0 ? fg_count : 1);  // gl*gv
        r.y = (fg_count > 0) ? 1.0f : 0.0f;                 // gv
        ws[g] = r;
    }
}

// Deterministic 8192 -> 1 reduction
__global__ __launch_bounds__(1024) void reduce_kernel(
    const float2* __restrict__ ws, float* __restrict__ out)
{
    __shared__ float sa[1024], sb[1024];
    const int t = threadIdx.x;
    float a = 0.0f, b2 = 0.0f;
    for (int g = t; g < GQ; g += 1024) {
        float2 v = ws[g];
        a += v.x; b2 += v.y;
    }
    sa[t] = a; sb[t] = b2;
    __syncthreads();
    for (int off = 512; off > 0; off >>= 1) {
        if (t < off) { sa[t] += sa[t + off]; sb[t] += sb[t + off]; }
        __syncthreads();
    }
    if (t == 0) out[0] = 0.1f * (sa[0] / sb[0]);
}

extern "C" void kernel_launch(void* const* d_in, const int* in_sizes, int n_in,
                              void* d_out, int out_size, void* d_ws, size_t ws_size,
                              hipStream_t stream) {
    const int*   labs  = (const int*)d_in[0];    // proposal_instance_mask
    const float* feats = (const float*)d_in[1];  // grouped_features
    const int*   idxs  = (const int*)d_in[2];    // grouped_indices
    const float* ctx   = (const float*)d_in[3];  // context_compen
    float* out = (float*)d_out;
    float2* ws = (float2*)d_ws;

    group_loss_kernel<<<NBLK, 64 * BLKG, 0, stream>>>(labs, feats, idxs, ctx, ws);
    reduce_kernel<<<1, 1024, 0, stream>>>(ws, out);
}

// Round 7
// 108.294 us; speedup vs baseline: 1.1567x; 1.1567x over previous
//
#include <hip/hip_runtime.h>

#define GQ    8192           // bs(32) * Gn(256)
#define BLKG  8              // groups per block (8 waves, 512 threads)
#define NBLK  (GQ / BLKG)    // 1024 blocks
#define MROW  132            // LDS row stride in floats (128 + 4: bank spread)
#define STG   (64 * MROW)    // staging floats per pass (64 channels)
#define SIMW  72             // per-wave sim scratch floats
#define SQRT5 2.23606797749978969f   // sqrt(1/T): folded so sim = dot/T

// Block = 8 waves = 8 consecutive groups (same batch b).
// TWO-PASS staging (32KB halves) -> LDS ~36KB -> 4 blocks/CU = 32 waves/CU.
// (Exact R5 structure: the pipelined/pinned variant R6 regressed 15us — the
//  compiler's own schedule of this simple form wins.)
// Gram: rows reduce-scattered over 64 lanes (descending-distance butterfly).
// LSE: lane-parallel (lane r = row r). NEW vs R5: block pre-reduces its 8
// group results -> ws[blk] (8KB total), shrinking the tail reduce dispatch.
__global__ __launch_bounds__(64 * BLKG, 8) void group_loss_kernel(
    const int*   __restrict__ labs,   // [G*16]
    const float* __restrict__ feats,  // [32,128,256,16]
    const int*   __restrict__ idxs,   // [G*16]
    const float* __restrict__ ctx,    // [128]
    float2*      __restrict__ ws)     // [NBLK] block partials {sum gl*gv, sum gv}
{
    __shared__ float SH[STG + BLKG * SIMW + 2 * BLKG];  // 36160 B -> 4 blocks/CU

    const int l  = threadIdx.x & 63;
    const int w  = threadIdx.x >> 6;            // wave id = local group id
    const int g0 = blockIdx.x * BLKG;
    const int g  = g0 + w;
    const int b  = g0 >> 8;                     // 8 | 256 -> same b for block
    const int gn0 = g0 & 255;
    float* SIM  = SH + STG + w * SIMW;
    float* PART = SH + STG + BLKG * SIMW;       // disjoint 16-float scratch

    const float* base = feats + (long)b * 524288 + (long)gn0 * 16;
    const int lo = l & 31;

    // ---- label/index loads (issue early) -----------------------------------
    int myidx = -1, mylab = -2;
    if (l < 16) { myidx = idxs[g * 16 + l]; mylab = labs[g * 16 + l]; }
    const float cx0 = ctx[l], cx1 = ctx[l + 64];

    // ---- stage pass A (channels 0..63): 4 x 512B-per-channel bursts --------
    #pragma unroll
    for (int k = 0; k < 4; ++k) {
        const int ch = w * 8 + k * 2 + (l >> 5);         // 0..63, unique
        const float4 v = *(const float4*)(base + (long)ch * 4096 + lo * 4);
        *(float4*)(SH + ch * MROW + lo * 4) = v;
    }

    // ---- ballots while stage loads are in flight ---------------------------
    unsigned long long mm = ~0ull;
    #pragma unroll
    for (int bit = 0; bit < 6; ++bit) {
        const unsigned long long bb = __ballot((myidx >> bit) & 1);
        mm &= ((myidx >> bit) & 1) ? bb : ~bb;
    }
    const bool dup = (mm & ((1ull << l) - 1) & 0xFFFFull) != 0ull;
    const int u = __popcll(__ballot((l < 16) && !dup));

    const bool valid = l < u;
    const int bid = valid ? (mylab + 1) : 255;  // bucket 0 = bg(-1), 1..8 = fg

    int cnt9[9];
    #pragma unroll
    for (int r = 0; r < 9; ++r) cnt9[r] = __popcll(__ballot(bid == r));
    const bool has_bg = cnt9[0] > 0;
    int fg_count = 0, pm = 0;
    #pragma unroll
    for (int r = 1; r < 9; ++r)
        if (cnt9[r] > 0) { ++fg_count; pm |= 1 << r; }

    float m0[9] = {0,0,0,0,0,0,0,0,0};
    float m1[9] = {0,0,0,0,0,0,0,0,0};

    // ---- consume pass A: lane l = channel l, chunked switch ----------------
    __syncthreads();
    {
        const float* R = SH + l * MROW + w * 16;
        #pragma unroll
        for (int q = 0; q < 4; ++q) {
            const float4 x = *(const float4*)(R + 4 * q);
            #pragma unroll
            for (int e = 0; e < 4; ++e) {
                const int s = 4 * q + e;
                if (s < u) {                                      // uniform
                    const int bs = __builtin_amdgcn_readlane(bid, s);
                    const float v = (e == 0) ? x.x : (e == 1) ? x.y
                                  : (e == 2) ? x.z : x.w;
                    switch (bs) {
                        case 0: m0[0] += v; break;  case 1: m0[1] += v; break;
                        case 2: m0[2] += v; break;  case 3: m0[3] += v; break;
                        case 4: m0[4] += v; break;  case 5: m0[5] += v; break;
                        case 6: m0[6] += v; break;  case 7: m0[7] += v; break;
                        case 8: m0[8] += v; break;
                    }
                }
            }
        }
    }
    __syncthreads();                             // all reads done before restage

    // ---- stage pass B (channels 64..127) -----------------------------------
    #pragma unroll
    for (int k = 0; k < 4; ++k) {
        const int ch = w * 8 + k * 2 + (l >> 5);
        const float4 v = *(const float4*)(base + (long)(64 + ch) * 4096 + lo * 4);
        *(float4*)(SH + ch * MROW + lo * 4) = v;
    }
    __syncthreads();

    // ---- consume pass B: lane l = channel l+64 -----------------------------
    {
        const float* R = SH + l * MROW + w * 16;
        #pragma unroll
        for (int q = 0; q < 4; ++q) {
            const float4 x = *(const float4*)(R + 4 * q);
            #pragma unroll
            for (int e = 0; e < 4; ++e) {
                const int s = 4 * q + e;
                if (s < u) {
                    const int bs = __builtin_amdgcn_readlane(bid, s);
                    const float v = (e == 0) ? x.x : (e == 1) ? x.y
                                  : (e == 2) ? x.z : x.w;
                    switch (bs) {
                        case 0: m1[0] += v; break;  case 1: m1[1] += v; break;
                        case 2: m1[2] += v; break;  case 3: m1[3] += v; break;
                        case 4: m1[4] += v; break;  case 5: m1[5] += v; break;
                        case 6: m1[6] += v; break;  case 7: m1[7] += v; break;
                        case 8: m1[8] += v; break;
                    }
                }
            }
        }
    }

    // ---- means scaled by sqrt(5) (carries 1/T in pair products) ------------
    #pragma unroll
    for (int r = 0; r < 9; ++r) {
        const float sc = SQRT5 / (float)(cnt9[r] > 0 ? cnt9[r] : 1);
        m0[r] *= sc; m1[r] *= sc;
    }
    if (!has_bg) { m0[0] = cx0 * SQRT5; m1[0] = cx1 * SQRT5; }

    // ---- Gram rows 1..8 via reduce-scatter: lane group l>>3 owns slot ------
    // Descending distances 32,16,8 scatter; 4,2,1 butterfly-complete.
    #pragma unroll
    for (int r = 1; r <= 8; ++r) {
        float p[8];
        #pragma unroll
        for (int j = 0; j < 8; ++j)
            p[j] = m0[r] * m0[j] + m1[r] * m1[j];
        #pragma unroll
        for (int i = 0; i < 4; ++i) {            // d=32: keep-lower/upper 4
            const float send = (l & 32) ? p[i] : p[i + 4];
            const float recv = __shfl_xor(send, 32);
            p[i] = ((l & 32) ? p[i + 4] : p[i]) + recv;
        }
        #pragma unroll
        for (int i = 0; i < 2; ++i) {            // d=16
            const float send = (l & 16) ? p[i] : p[i + 2];
            const float recv = __shfl_xor(send, 16);
            p[i] = ((l & 16) ? p[i + 2] : p[i]) + recv;
        }
        {                                        // d=8
            const float send = (l & 8) ? p[0] : p[1];
            const float recv = __shfl_xor(send, 8);
            p[0] = ((l & 8) ? p[1] : p[0]) + recv;
        }
        p[0] += __shfl_xor(p[0], 4);
        p[0] += __shfl_xor(p[0], 2);
        p[0] += __shfl_xor(p[0], 1);
        if ((l & 7) == 0) SIM[(r - 1) * 8 + (l >> 3)] = p[0];
    }
    // sim[8][8]: full butterfly, all lanes hold total
    float s88 = m0[8] * m0[8] + m1[8] * m1[8];
    s88 += __shfl_xor(s88, 1);  s88 += __shfl_xor(s88, 2);
    s88 += __shfl_xor(s88, 4);  s88 += __shfl_xor(s88, 8);
    s88 += __shfl_xor(s88, 16); s88 += __shfl_xor(s88, 32);

    // ---- lane-parallel masked LSE: lane r = row r (1..8) -------------------
    const int cm = pm | 1;                       // col 0 (bg/ctx) always valid
    const float NINF = __int_as_float(0xFF800000);
    float li = 0.0f;
    if (l >= 1 && l <= 8) {
        const float* Rw = SIM + (l - 1) * 8;
        const float4 ra = *(const float4*)(Rw);
        const float4 rb = *(const float4*)(Rw + 4);
        const float s8 = SIM[56 + l];            // junk for l==8 (slot 64, in-range)
        float srow[9] = { ra.x, ra.y, ra.z, ra.w, rb.x, rb.y, rb.z, rb.w,
                          (l == 8) ? s88 : s8 };
        float vmax = NINF, diag = 0.0f, v[9];
        #pragma unroll
        for (int j = 0; j < 9; ++j) {
            v[j] = ((cm >> j) & 1) ? srow[j] : NINF;
            vmax = fmaxf(vmax, v[j]);
            if (j >= 1) diag = (l == j) ? srow[j] : diag;
        }
        float se = 0.0f;
        #pragma unroll
        for (int j = 0; j < 9; ++j) se += __expf(v[j] - vmax);  // exp(-inf)=0
        li = vmax + __logf(se) - diag;
        li = ((pm >> l) & 1) ? li : 0.0f;        // absent row contributes 0
    }

    // ---- sum li over lanes 1..8 -> lane 0 ----------------------------------
    float ssum = li;
    ssum += __shfl_down(ssum, 8);
    ssum += __shfl_down(ssum, 4);
    ssum += __shfl_down(ssum, 2);
    ssum += __shfl_down(ssum, 1);

    // ---- block pre-reduce: 8 wave results -> one float2 partial ------------
    if (l == 0) {
        PART[2 * w]     = ssum / (float)(fg_count > 0 ? fg_count : 1);  // gl*gv
        PART[2 * w + 1] = (fg_count > 0) ? 1.0f : 0.0f;                 // gv
    }
    __syncthreads();
    if (threadIdx.x == 0) {
        float px = 0.0f, py = 0.0f;
        #pragma unroll
        for (int i = 0; i < BLKG; ++i) { px += PART[2 * i]; py += PART[2 * i + 1]; }
        ws[blockIdx.x] = make_float2(px, py);
    }
}

// Deterministic 1024 -> 1 reduction (8 KB read, 256 threads)
__global__ __launch_bounds__(256) void reduce_kernel(
    const float2* __restrict__ ws, float* __restrict__ out)
{
    __shared__ float sa[256], sb[256];
    const int t = threadIdx.x;
    float a = 0.0f, b2 = 0.0f;
    #pragma unroll
    for (int i = 0; i < NBLK / 256; ++i) {
        const float2 v = ws[t + i * 256];
        a += v.x; b2 += v.y;
    }
    sa[t] = a; sb[t] = b2;
    __syncthreads();
    for (int off = 128; off > 0; off >>= 1) {
        if (t < off) { sa[t] += sa[t + off]; sb[t] += sb[t + off]; }
        __syncthreads();
    }
    if (t == 0) out[0] = 0.1f * (sa[0] / sb[0]);
}

extern "C" void kernel_launch(void* const* d_in, const int* in_sizes, int n_in,
                              void* d_out, int out_size, void* d_ws, size_t ws_size,
                              hipStream_t stream) {
    const int*   labs  = (const int*)d_in[0];    // proposal_instance_mask
    const float* feats = (const float*)d_in[1];  // grouped_features
    const int*   idxs  = (const int*)d_in[2];    // grouped_indices
    const float* ctx   = (const float*)d_in[3];  // context_compen
    float* out = (float*)d_out;
    float2* ws = (float2*)d_ws;

    group_loss_kernel<<<NBLK, 64 * BLKG, 0, stream>>>(labs, feats, idxs, ctx, ws);
    reduce_kernel<<<1, 256, 0, stream>>>(ws, out);
}